// Round 1
// 264.219 us; speedup vs baseline: 1.0228x; 1.0228x over previous
//
#include <hip/hip_runtime.h>
#include <hip/hip_bf16.h>

typedef __hip_bfloat16 bf16;
typedef __attribute__((ext_vector_type(8))) short short8;
typedef __attribute__((ext_vector_type(4))) short short4v;
typedef __attribute__((ext_vector_type(4))) float f32x4;

#define MFMA_BF16(a, b, c) __builtin_amdgcn_mfma_f32_16x16x32_bf16((a), (b), (c), 0, 0, 0)

// 1/sqrt(E/H) * log2(e) folded into Wqkv q-rows: softmax exps become plain exp2
#define QSCALE 0.1803368860111270f

__device__ __forceinline__ short f2bf(float f) {
    union { bf16 h; short s; } u;
    u.h = __float2bfloat16(f);
    return u.s;
}

#if defined(__has_builtin) && __has_builtin(__builtin_amdgcn_cvt_pk_bf16_f32)
typedef __attribute__((ext_vector_type(2))) __bf16 bf16x2_t;
__device__ __forceinline__ unsigned int pk2(float a, float b) {
    union { bf16x2_t v; unsigned int u; } x;
    x.v = __builtin_amdgcn_cvt_pk_bf16_f32(a, b);
    return x.u;
}
#else
__device__ __forceinline__ unsigned int pk2(float a, float b) {
    union { bf16 h[2]; unsigned int u; } x;
    x.h[0] = __float2bfloat16(a);
    x.h[1] = __float2bfloat16(b);
    return x.u;
}
#endif

// async global->LDS, 16B per lane; dest = wave-uniform base + lane*16 (linear)
__device__ __forceinline__ void gload16(const void* g, void* l) {
    __builtin_amdgcn_global_load_lds(
        (const __attribute__((address_space(1))) unsigned int*)g,
        (__attribute__((address_space(3))) unsigned int*)l, 16, 0, 0);
}

// ---------------- ALL converts in one dispatch (grid.y selects tensor / mode) ----------------
// y=0..3: plain convert (x, y, Wout1, Wout2). y=4,5: Wqkv row-permute + q-scale.
__global__ void cvt_fused(const float* __restrict__ x, const float* __restrict__ y,
                          const float* __restrict__ wo1, const float* __restrict__ wo2,
                          const float* __restrict__ wq1, const float* __restrict__ wq2,
                          bf16* __restrict__ ox, bf16* __restrict__ oy,
                          bf16* __restrict__ oo1, bf16* __restrict__ oo2,
                          bf16* __restrict__ oq1, bf16* __restrict__ oq2) {
    const int yb = blockIdx.y;
    if (yb < 4) {
        int i = blockIdx.x * 256 + threadIdx.x;
        const float* src; bf16* dst; int n4;
        switch (yb) {
            case 0:  src = x;   dst = ox;  n4 = 1048576; break;
            case 1:  src = y;   dst = oy;  n4 = 1048576; break;
            case 2:  src = wo1; dst = oo1; n4 = 262144;  break;
            default: src = wo2; dst = oo2; n4 = 262144;  break;
        }
        if (i >= n4) return;
        float4 f = reinterpret_cast<const float4*>(src)[i];
        short4v s;
        s.x = f2bf(f.x); s.y = f2bf(f.y); s.z = f2bf(f.z); s.w = f2bf(f.w);
        reinterpret_cast<short4v*>(dst)[i] = s;
    } else {
        // dest row n' = comp*1024 + h*64 + d  <-  src row d*48 + comp*16 + h
        const int np = blockIdx.x;
        if (np >= 3072) return;
        const int comp = np >> 10, rem = np & 1023, h = rem >> 6, d = rem & 63;
        const int srow = d * 48 + comp * 16 + h;
        const float* src = ((yb == 5) ? wq2 : wq1) + (long)srow * 1024;
        bf16* dst = ((yb == 5) ? oq2 : oq1) + (long)np * 1024;
        const float sc = (comp == 0) ? QSCALE : 1.0f;
        int t = threadIdx.x;
        float4 f = reinterpret_cast<const float4*>(src)[t];
        short4v s;
        s.x = f2bf(f.x * sc); s.y = f2bf(f.y * sc); s.z = f2bf(f.z * sc); s.w = f2bf(f.w * sc);
        reinterpret_cast<short4v*>(dst)[t] = s;
    }
}

// ---------------- GEMM: global_load_lds dbuf K-loop (m97 structure + 2-way swizzle) ----------------
// 128x128 tile, BK=32, K=1024 (32 iters). Staging via global_load_lds width=16:
// LDS dest linear [128 rows][32 shorts]; source chunk pre-swizzled (lane&3)^(row&3),
// frag ds_read applies the same XOR (slot = quad ^ (l16&3)) -> 2-way bank alias = free.
// One barrier/iter (compiler drains vmcnt(0) there): tile k+1 loads fly over tile k MFMA.
// MODE 0 (qkv): N=3072; blocks x<8 write q packed [bh][t][d], x in 8..15 write k packed,
//               x in 16..23 LDS-transpose V -> vT [bh][d][t]. q pre-scaled via weights.
// MODE 1 (out-proj): N=1024; fp32 C.
template <int MODE>
__global__ __launch_bounds__(256)
void gemm_k(const bf16* __restrict__ A0g, const bf16* __restrict__ B0g,
            void* o0a, void* o0b, void* o0c,
            const bf16* __restrict__ A1g, const bf16* __restrict__ B1g,
            void* o1a, void* o1b, void* o1c, int N) {
    __shared__ short smem[20480];   // staging: 2 bufs x (A 4096 + B 4096) shorts = 32KB; epilogue transpose needs 36KB
    const int z = blockIdx.z;
    const short* A = reinterpret_cast<const short*>(z ? A1g : A0g);
    const short* B = reinterpret_cast<const short*>(z ? B1g : B0g);
    const int tid  = threadIdx.x;
    const int lane = tid & 63;
    const int w    = tid >> 6;
    const int wr   = w >> 1;
    const int wc   = w & 1;
    const int quad = lane >> 4;
    const int l16  = lane & 15;
    const long bM = (long)blockIdx.y * 128;

    f32x4 acc[4][4] = {};

    // staging: wave w covers rows 32w..32w+31 of A-tile and B-tile (2 segs x 16 rows each)
    const int sr  = lane >> 2;                       // row within 16-row seg
    const int scs = ((lane & 3) ^ (sr & 3)) * 8;     // swizzled 16B source chunk (shorts)
    const short* Ag0 = A + (bM + 32 * w + sr) * 1024 + scs;
    const short* Ag1 = Ag0 + 16 * 1024;
    const short* Bg0 = B + ((long)blockIdx.x * 128 + 32 * w + sr) * 1024 + scs;
    const short* Bg1 = Bg0 + 16 * 1024;

    // frag-read slot: LDS(row, slot) holds G(row, slot ^ (row&3)); row&3 == l16&3
    const int sq = (quad ^ (l16 & 3)) * 8;

    // prologue: tile 0 -> buf 0
    {
        short* sb = smem;
        gload16(Ag0, sb + w * 1024);
        gload16(Ag1, sb + w * 1024 + 512);
        gload16(Bg0, sb + 4096 + w * 1024);
        gload16(Bg1, sb + 4096 + w * 1024 + 512);
    }
    __syncthreads();

    for (int iter = 0; iter < 32; ++iter) {
        const int cur = iter & 1;
        if (iter < 31) {
            const int koff = (iter + 1) * 32;
            short* sb = smem + (cur ^ 1) * 8192;
            gload16(Ag0 + koff, sb + w * 1024);
            gload16(Ag1 + koff, sb + w * 1024 + 512);
            gload16(Bg0 + koff, sb + 4096 + w * 1024);
            gload16(Bg1 + koff, sb + 4096 + w * 1024 + 512);
        }
        const short* Ab = smem + cur * 8192;
        const short* Bb = Ab + 4096;

        short8 af[4], bfr[4];
#pragma unroll
        for (int mt = 0; mt < 4; ++mt)
            af[mt] = *reinterpret_cast<const short8*>(&Ab[(wr * 64 + mt * 16 + l16) * 32 + sq]);
#pragma unroll
        for (int nt = 0; nt < 4; ++nt)
            bfr[nt] = *reinterpret_cast<const short8*>(&Bb[(wc * 64 + nt * 16 + l16) * 32 + sq]);
#pragma unroll
        for (int mt = 0; mt < 4; ++mt)
#pragma unroll
            for (int nt = 0; nt < 4; ++nt)
                acc[mt][nt] = MFMA_BF16(af[mt], bfr[nt], acc[mt][nt]);

        __syncthreads();
    }

    if (MODE == 1) {
        float* C = reinterpret_cast<float*>(z ? o1a : o0a);
        const long crow = bM + wr * 64 + quad * 4;
        const long ccol = (long)blockIdx.x * 128 + wc * 64 + l16;
#pragma unroll
        for (int mt = 0; mt < 4; ++mt)
#pragma unroll
            for (int nt = 0; nt < 4; ++nt)
#pragma unroll
                for (int r = 0; r < 4; ++r)
                    C[(crow + mt * 16 + r) * (long)N + ccol + nt * 16] = acc[mt][nt][r];
        return;
    }

    // MODE 0 epilogue
    if (blockIdx.x < 16) {
        // q (x<8) / k (x in 8..15), packed [bh][t][d]
        short* dst = reinterpret_cast<short*>(blockIdx.x >= 8 ? (z ? o1b : o0b)
                                                              : (z ? o1a : o0a));
        const int hd0 = (int)(blockIdx.x & 7) * 128 + wc * 64;  // + nt*16 + l16 -> h*64+d
        const int b = (int)(bM >> 10);
        const int t0 = ((int)bM & 1023) + wr * 64 + quad * 4;
#pragma unroll
        for (int nt = 0; nt < 4; ++nt) {
            const int hd = hd0 + nt * 16 + l16;
            const int h = hd >> 6, d = hd & 63;
            short* dp = dst + ((long)(b * 16 + h) * 1024) * 64 + d;
#pragma unroll
            for (int mt = 0; mt < 4; ++mt)
#pragma unroll
                for (int r = 0; r < 4; ++r)
                    dp[(long)(t0 + mt * 16 + r) * 64] = f2bf(acc[mt][nt][r]);
        }
    } else {
        // V: LDS-transpose wave tile -> vT [bh][d][t] with coalesced 16B stores
        short* vT = reinterpret_cast<short*>(z ? o1c : o0c);
        const int h = ((int)blockIdx.x - 16) * 2 + wc;
        const int b = (int)(bM >> 10);
        const int tb = ((int)bM & 1023) + wr * 64;
        short* ws = smem + w * 4608;    // 64 d-rows x 72 shorts, wave-private
#pragma unroll
        for (int nt = 0; nt < 4; ++nt)
#pragma unroll
            for (int mt = 0; mt < 4; ++mt) {
                uint2 uu;
                uu.x = pk2(acc[mt][nt][0], acc[mt][nt][1]);
                uu.y = pk2(acc[mt][nt][2], acc[mt][nt][3]);
                *reinterpret_cast<uint2*>(&ws[(nt * 16 + l16) * 72 + mt * 16 + quad * 4]) = uu;
            }
        // wave-private region: same-wave DS ordering suffices, no barrier
        short* vbase = vT + (long)(b * 16 + h) * 64 * 1024;
#pragma unroll
        for (int p = 0; p < 8; ++p) {
            const int d = p * 8 + (lane >> 3);
            const int ch = (lane & 7) * 8;
            short8 v = *reinterpret_cast<const short8*>(&ws[d * 72 + ch]);
            *reinterpret_cast<short8*>(&vbase[(long)d * 1024 + tb + ch]) = v;
        }
    }
}

// ---------------- flash attention, S^T formulation + global_load_lds K/V staging ----------------
// Q,K packed [bh][t][d] (stride 64); V^T [bh][d][t]. grid.x = bh (same-bh blocks land on
// one XCD -> K/V L2-resident), grid.y = qt (128 queries), grid.z = stream.
// K/V tiles [64][64 shorts] linear in LDS via global_load_lds; source chunk pre-swizzled
// (lane&7)^(row&7); reads XOR the same -> K 2-way (free), V conflict-free.
__global__ __launch_bounds__(256)
void attn_kernel(const bf16* __restrict__ q0g, const bf16* __restrict__ k0g,
                 const bf16* __restrict__ v0g, bf16* __restrict__ o0g,
                 const bf16* __restrict__ q1g, const bf16* __restrict__ k1g,
                 const bf16* __restrict__ v1g, bf16* __restrict__ o1g) {
    __shared__ short smem[16384];   // 2 bufs x (K 4096 + V 4096) shorts = 32KB
    const int bh = blockIdx.x;
    const int qt = blockIdx.y;
    const int z = blockIdx.z;
    const int b = bh >> 4, h = bh & 15;
    const int tid = threadIdx.x, lane = tid & 63, w = tid >> 6;
    const int quad = lane >> 4, l16 = lane & 15;

    const short* Qb = reinterpret_cast<const short*>(z ? q1g : q0g) + (long)bh * 1024 * 64;
    const short* Kb = reinterpret_cast<const short*>(z ? k1g : k0g) + (long)bh * 1024 * 64;
    const short* Vb = reinterpret_cast<const short*>(z ? v1g : v0g) + (long)bh * 64 * 1024;
    short* Ob = reinterpret_cast<short*>(z ? o1g : o0g);

    short8 qb[2][2];
#pragma unroll
    for (int qg = 0; qg < 2; ++qg) {
        const short* Qp = Qb + (long)(qt * 128 + qg * 64 + w * 16 + l16) * 64;
        qb[qg][0] = *reinterpret_cast<const short8*>(Qp + quad * 8);
        qb[qg][1] = *reinterpret_cast<const short8*>(Qp + 32 + quad * 8);
    }

    // staging: wave w covers rows 16w..16w+15 (2 segs x 8 rows) of K-tile and V-tile
    const int r8  = lane >> 3;
    const int sc8 = ((lane & 7) ^ r8) * 8;   // swizzled 16B source chunk (shorts)
    const short* Kg0 = Kb + (long)(16 * w + r8) * 64 + sc8;
    const short* Kg1 = Kg0 + 8 * 64;
    const short* Vg0 = Vb + (long)(16 * w + r8) * 1024 + sc8;
    const short* Vg1 = Vg0 + 8 * 1024;

    const int jbase = 8 * (l16 >> 2) + (l16 & 3);

    f32x4 o[2][4] = {};
    float li[2] = {0.f, 0.f};

    {
        short* sb = smem;
        gload16(Kg0, sb + w * 1024);
        gload16(Kg1, sb + w * 1024 + 512);
        gload16(Vg0, sb + 4096 + w * 1024);
        gload16(Vg1, sb + 4096 + w * 1024 + 512);
    }
    __syncthreads();

    for (int iter = 0; iter < 16; ++iter) {
        const int cur = iter & 1;
        if (iter < 15) {
            const long ko = (long)(iter + 1) * 4096;   // 64 t-rows * 64 shorts
            const long vo = (long)(iter + 1) * 64;     // within-row t offset
            short* sb = smem + (cur ^ 1) * 8192;
            gload16(Kg0 + ko, sb + w * 1024);
            gload16(Kg1 + ko, sb + w * 1024 + 512);
            gload16(Vg0 + vo, sb + 4096 + w * 1024);
            gload16(Vg1 + vo, sb + 4096 + w * 1024 + 512);
        }
        const short* Ks = smem + cur * 8192;
        const short* Vs = Ks + 4096;

        f32x4 st[2][4];
#pragma unroll
        for (int g = 0; g < 4; ++g) {
            const int goff = (g >> 1) * 32 + (g & 1) * 4;
            const int row = jbase + goff;
            const int s0 = (quad ^ (row & 7)) * 8;
            const short* kr = Ks + row * 64;
            short8 k0 = *reinterpret_cast<const short8*>(kr + s0);
            short8 k1 = *reinterpret_cast<const short8*>(kr + (s0 ^ 32));
#pragma unroll
            for (int qg = 0; qg < 2; ++qg) {
                f32x4 zf = {0.f, 0.f, 0.f, 0.f};
                zf = MFMA_BF16(k0, qb[qg][0], zf);
                zf = MFMA_BF16(k1, qb[qg][1], zf);
                st[qg][g] = zf;
            }
        }

        union { unsigned int u[4]; short8 s; } f0[2], f1[2];
#pragma unroll
        for (int qg = 0; qg < 2; ++qg) {
            float p[4][4];
            float rs = 0.f;
#pragma unroll
            for (int g = 0; g < 4; ++g)
#pragma unroll
                for (int r = 0; r < 4; ++r) {
                    float e = exp2f(st[qg][g][r]);
                    p[g][r] = e;
                    rs += e;
                }
            li[qg] += rs;
            f0[qg].u[0] = pk2(p[0][0], p[0][1]); f0[qg].u[1] = pk2(p[0][2], p[0][3]);
            f0[qg].u[2] = pk2(p[1][0], p[1][1]); f0[qg].u[3] = pk2(p[1][2], p[1][3]);
            f1[qg].u[0] = pk2(p[2][0], p[2][1]); f1[qg].u[1] = pk2(p[2][2], p[2][3]);
            f1[qg].u[2] = pk2(p[3][0], p[3][1]); f1[qg].u[3] = pk2(p[3][2], p[3][3]);
        }

#pragma unroll
        for (int dt = 0; dt < 4; ++dt) {
            const int rv = dt * 16 + l16;
            const int sv = (quad ^ (rv & 7)) * 8;
            const short* vr = Vs + rv * 64;
            short8 v0 = *reinterpret_cast<const short8*>(vr + sv);
            short8 v1 = *reinterpret_cast<const short8*>(vr + (sv ^ 32));
#pragma unroll
            for (int qg = 0; qg < 2; ++qg) {
                o[qg][dt] = MFMA_BF16(v0, f0[qg].s, o[qg][dt]);
                o[qg][dt] = MFMA_BF16(v1, f1[qg].s, o[qg][dt]);
            }
        }

        __syncthreads();
    }

#pragma unroll
    for (int qg = 0; qg < 2; ++qg) {
        li[qg] += __shfl_xor(li[qg], 16);
        li[qg] += __shfl_xor(li[qg], 32);
    }

#pragma unroll
    for (int qg = 0; qg < 2; ++qg) {
        short* Os = smem + qg * 5120 + w * 1280;
        const float rl = 1.0f / li[qg];
#pragma unroll
        for (int dt = 0; dt < 4; ++dt) {
            uint2 uu;
            uu.x = pk2(o[qg][dt][0] * rl, o[qg][dt][1] * rl);
            uu.y = pk2(o[qg][dt][2] * rl, o[qg][dt][3] * rl);
            *reinterpret_cast<uint2*>(&Os[l16 * 80 + dt * 16 + quad * 4]) = uu;
        }
#pragma unroll
        for (int p = 0; p < 2; ++p) {
            int row = p * 8 + (lane >> 3);
            int ch = (lane & 7) * 8;
            short8 v = *reinterpret_cast<const short8*>(&Os[row * 80 + ch]);
            *reinterpret_cast<short8*>(&Ob[((long)(b * 1024) + qt * 128 + qg * 64 + w * 16 + row) * 1024 + h * 64 + ch]) = v;
        }
    }
}

extern "C" void kernel_launch(void* const* d_in, const int* in_sizes, int n_in,
                              void* d_out, int out_size, void* d_ws, size_t ws_size,
                              hipStream_t stream) {
    const float* x     = (const float*)d_in[0];
    const float* y     = (const float*)d_in[1];
    const float* Wqkv1 = (const float*)d_in[2];
    const float* Wqkv2 = (const float*)d_in[3];
    const float* Wout1 = (const float*)d_in[4];
    const float* Wout2 = (const float*)d_in[5];

    char* ws = (char*)d_ws;
    bf16* Wqkv1b = (bf16*)(ws + 0);          // 6291456
    bf16* Wqkv2b = (bf16*)(ws + 6291456);    // 6291456
    bf16* Wout1b = (bf16*)(ws + 12582912);   // 2097152
    bf16* Wout2b = (bf16*)(ws + 14680064);   // 2097152
    bf16* xb     = (bf16*)(ws + 16777216);   // 8388608
    bf16* yb     = (bf16*)(ws + 25165824);   // 8388608
    bf16* q1     = (bf16*)(ws + 33554432);   // 8388608  packed [bh][t][d]
    bf16* k1     = (bf16*)(ws + 41943040);   // 8388608
    bf16* v1T    = (bf16*)(ws + 50331648);   // 8388608  [bh][d][t]
    bf16* q2     = (bf16*)(ws + 58720256);   // 8388608
    bf16* k2     = (bf16*)(ws + 67108864);   // 8388608
    bf16* v2T    = (bf16*)(ws + 75497472);   // 8388608 -> 83886080 (80 MB)
    bf16* xo     = xb;                       // xb dead after qkv GEMM
    bf16* yo     = yb;

    // 1. all converts (x, y, Wout, Wqkv-permuted+scaled)
    cvt_fused<<<dim3(4096, 6), 256, 0, stream>>>(x, y, Wout1, Wout2, Wqkv1, Wqkv2,
                                                 xb, yb, Wout1b, Wout2b, Wqkv1b, Wqkv2b);

    // 2. qkv GEMM (global_load_lds pipeline) -> q,k packed + vT directly; both streams
    gemm_k<0><<<dim3(24, 32, 2), 256, 0, stream>>>(xb, Wqkv1b, q1, k1, v1T,
                                                   yb, Wqkv2b, q2, k2, v2T, 3072);

    // 3. cross attention: z=0: softmax(q2 k1^T) v1 -> xo ; z=1: softmax(q1 k2^T) v2 -> yo
    attn_kernel<<<dim3(64, 8, 2), 256, 0, stream>>>(q2, k1, v1T, xo,
                                                    q1, k2, v2T, yo);

    // 4. output projections (global_load_lds pipeline, fp32 epilogue)
    gemm_k<1><<<dim3(8, 32, 2), 256, 0, stream>>>(xo, Wout1b, (float*)d_out, nullptr, nullptr,
                                                  yo, Wout2b, ((float*)d_out) + 4194304, nullptr, nullptr,
                                                  1024);
}

// Round 2
// 263.933 us; speedup vs baseline: 1.0239x; 1.0011x over previous
//
#include <hip/hip_runtime.h>
#include <hip/hip_bf16.h>

typedef __hip_bfloat16 bf16;
typedef __attribute__((ext_vector_type(8))) short short8;
typedef __attribute__((ext_vector_type(4))) short short4v;
typedef __attribute__((ext_vector_type(4))) float f32x4;

#define MFMA_BF16(a, b, c) __builtin_amdgcn_mfma_f32_16x16x32_bf16((a), (b), (c), 0, 0, 0)

// 1/sqrt(E/H) * log2(e) folded into Wqkv q-rows: softmax exps become plain exp2
#define QSCALE 0.1803368860111270f

__device__ __forceinline__ short f2bf(float f) {
    union { bf16 h; short s; } u;
    u.h = __float2bfloat16(f);
    return u.s;
}

#if defined(__has_builtin) && __has_builtin(__builtin_amdgcn_cvt_pk_bf16_f32)
typedef __attribute__((ext_vector_type(2))) __bf16 bf16x2_t;
__device__ __forceinline__ unsigned int pk2(float a, float b) {
    union { bf16x2_t v; unsigned int u; } x;
    x.v = __builtin_amdgcn_cvt_pk_bf16_f32(a, b);
    return x.u;
}
#else
__device__ __forceinline__ unsigned int pk2(float a, float b) {
    union { bf16 h[2]; unsigned int u; } x;
    x.h[0] = __float2bfloat16(a);
    x.h[1] = __float2bfloat16(b);
    return x.u;
}
#endif

// async global->LDS, 16B per lane; dest = wave-uniform base + lane*16 (linear)
__device__ __forceinline__ void gload16(const void* g, void* l) {
    __builtin_amdgcn_global_load_lds(
        (const __attribute__((address_space(1))) unsigned int*)g,
        (__attribute__((address_space(3))) unsigned int*)l, 16, 0, 0);
}

// ---------------- ALL converts in one dispatch (grid.y selects tensor / mode) ----------------
__global__ void cvt_fused(const float* __restrict__ x, const float* __restrict__ y,
                          const float* __restrict__ wo1, const float* __restrict__ wo2,
                          const float* __restrict__ wq1, const float* __restrict__ wq2,
                          bf16* __restrict__ ox, bf16* __restrict__ oy,
                          bf16* __restrict__ oo1, bf16* __restrict__ oo2,
                          bf16* __restrict__ oq1, bf16* __restrict__ oq2) {
    const int yb = blockIdx.y;
    if (yb < 4) {
        int i = blockIdx.x * 256 + threadIdx.x;
        const float* src; bf16* dst; int n4;
        switch (yb) {
            case 0:  src = x;   dst = ox;  n4 = 1048576; break;
            case 1:  src = y;   dst = oy;  n4 = 1048576; break;
            case 2:  src = wo1; dst = oo1; n4 = 262144;  break;
            default: src = wo2; dst = oo2; n4 = 262144;  break;
        }
        if (i >= n4) return;
        float4 f = reinterpret_cast<const float4*>(src)[i];
        short4v s;
        s.x = f2bf(f.x); s.y = f2bf(f.y); s.z = f2bf(f.z); s.w = f2bf(f.w);
        reinterpret_cast<short4v*>(dst)[i] = s;
    } else {
        // dest row n' = comp*1024 + h*64 + d  <-  src row d*48 + comp*16 + h
        const int np = blockIdx.x;
        if (np >= 3072) return;
        const int comp = np >> 10, rem = np & 1023, h = rem >> 6, d = rem & 63;
        const int srow = d * 48 + comp * 16 + h;
        const float* src = ((yb == 5) ? wq2 : wq1) + (long)srow * 1024;
        bf16* dst = ((yb == 5) ? oq2 : oq1) + (long)np * 1024;
        const float sc = (comp == 0) ? QSCALE : 1.0f;
        int t = threadIdx.x;
        float4 f = reinterpret_cast<const float4*>(src)[t];
        short4v s;
        s.x = f2bf(f.x * sc); s.y = f2bf(f.y * sc); s.z = f2bf(f.z * sc); s.w = f2bf(f.w * sc);
        reinterpret_cast<short4v*>(dst)[t] = s;
    }
}

// ---------------- 256x256 8-phase qkv GEMM (T2+T3+T4+T5), BK=64, 8 waves ----------------
// LDS 128KB dynamic: 2 bufs x {A0,A1,B0,B1} halves of [128 rows][64 shorts] linear.
// Stage stream per K-tile: H0=A0, H1=B0, H2=B1, H3=A1, one half per phase via
// global_load_lds (source chunk pre-swizzled c^(row&7); reads XOR the same -> conflict-free).
// Phase regions (Ah,Bh): (0,0),(0,1),(1,0),(1,1); A-frags held across phase pairs.
// Counted gates: vmcnt(4)+s_barrier at phases 0,1,2 (derivation: 2 half-tiles always in
// flight past the needed one); no gate at phase 3; never vmcnt(0) in the loop.
// Epilogue: x<4 -> q packed [bh][t][d], 4..7 -> k packed, 8..11 -> LDS-transpose V -> [bh][d][t].
#define GATE4 do { asm volatile("s_waitcnt vmcnt(4)" ::: "memory"); \
    __builtin_amdgcn_s_barrier(); __builtin_amdgcn_sched_barrier(0); } while (0)

__global__ __launch_bounds__(512, 2)
void gemm_qkv256(const bf16* __restrict__ A0g, const bf16* __restrict__ B0g,
                 void* o0a, void* o0b, void* o0c,
                 const bf16* __restrict__ A1g, const bf16* __restrict__ B1g,
                 void* o1a, void* o1b, void* o1c) {
    extern __shared__ short smem[];   // 65536 shorts = 128KB
    const int z = blockIdx.z;
    const short* A = reinterpret_cast<const short*>(z ? A1g : A0g);
    const short* B = reinterpret_cast<const short*>(z ? B1g : B0g);
    const int tid  = threadIdx.x;
    const int lane = tid & 63;
    const int w    = tid >> 6;        // 0..7
    const int quad = lane >> 4;
    const int l16  = lane & 15;
    const long M0 = (long)blockIdx.y * 256;
    const long N0 = (long)blockIdx.x * 256;

    const int rowblk = (w >> 2) * 64;     // wave M-offset within 128-row region
    const int colblk = (w & 3) * 32;      // wave N-offset within 128-col region
    const int cA0  = (quad ^ (l16 & 7)) * 8;            // kk=0 chunk (shorts); kk=1 -> ^32
    const int aoff = (rowblk + l16) * 64;
    const int boff = 16384 + (colblk + l16) * 64;       // B halves live at +16384/+24576
    const int w512 = w * 512;

    const short* Asrc = A + (M0 + w * 8 + (lane >> 3)) * 1024 + ((lane & 7) ^ (lane >> 3)) * 8;
    const short* Bsrc = B + (N0 + w * 8 + (lane >> 3)) * 1024 + ((lane & 7) ^ (lane >> 3)) * 8;

    f32x4 acc[4][4][2] = {};
    short8 af[4][2], bfv[2][2];

#define SA256(half, tt, nbase) do { \
    const short* _s = Asrc + (half) * 131072 + (tt) * 64; \
    short* _d = smem + (nbase) + (half) * 8192 + w512; \
    gload16(_s, _d); gload16(_s + 65536, _d + 4096); } while (0)
#define SB256(half, tt, nbase) do { \
    const short* _s = Bsrc + (half) * 131072 + (tt) * 64; \
    short* _d = smem + (nbase) + 16384 + (half) * 8192 + w512; \
    gload16(_s, _d); gload16(_s + 65536, _d + 4096); } while (0)
#define RDA256(Ah, bbv) do { \
    _Pragma("unroll") for (int mt = 0; mt < 4; ++mt) { \
        const short* _p = &smem[(bbv) + (Ah) * 8192 + aoff + mt * 1024]; \
        af[mt][0] = *reinterpret_cast<const short8*>(_p + cA0); \
        af[mt][1] = *reinterpret_cast<const short8*>(_p + (cA0 ^ 32)); } } while (0)
#define RDB256(Bh, bbv) do { \
    _Pragma("unroll") for (int nt = 0; nt < 2; ++nt) { \
        const short* _p = &smem[(bbv) + (Bh) * 8192 + boff + nt * 1024]; \
        bfv[nt][0] = *reinterpret_cast<const short8*>(_p + cA0); \
        bfv[nt][1] = *reinterpret_cast<const short8*>(_p + (cA0 ^ 32)); } } while (0)
#define MM256(p) do { \
    __builtin_amdgcn_s_setprio(1); \
    _Pragma("unroll") for (int mt = 0; mt < 4; ++mt) \
    _Pragma("unroll") for (int nt = 0; nt < 2; ++nt) { \
        acc[p][mt][nt] = MFMA_BF16(af[mt][0], bfv[nt][0], acc[p][mt][nt]); \
        acc[p][mt][nt] = MFMA_BF16(af[mt][1], bfv[nt][1], acc[p][mt][nt]); } \
    __builtin_amdgcn_s_setprio(0); } while (0)

    // prologue: K-tile 0 fully staged into buf0 (stream order A0,B0,B1,A1)
    SA256(0, 0, 0); SB256(0, 0, 0); SB256(1, 0, 0); SA256(1, 0, 0);

#pragma unroll 1
    for (int t = 0; t < 15; ++t) {
        const int bb = (t & 1) << 15;
        const int nb = bb ^ 32768;
        // phase 0: region (A0,B0); stage H0(t+1)=A0
        GATE4;
        SA256(0, t + 1, nb);
        RDA256(0, bb); RDB256(0, bb);
        __builtin_amdgcn_sched_barrier(0);
        MM256(0);
        // phase 1: region (A0,B1); stage H1(t+1)=B0
        GATE4;
        SB256(0, t + 1, nb);
        RDB256(1, bb);
        __builtin_amdgcn_sched_barrier(0);
        MM256(1);
        // phase 2: region (A1,B0); stage H2(t+1)=B1
        GATE4;
        SB256(1, t + 1, nb);
        RDA256(1, bb); RDB256(0, bb);
        __builtin_amdgcn_sched_barrier(0);
        MM256(2);
        // phase 3: region (A1,B1); stage H3(t+1)=A1 (no gate needed: B1 gated at p1)
        SA256(1, t + 1, nb);
        RDB256(1, bb);
        __builtin_amdgcn_sched_barrier(0);
        MM256(3);
    }
    // tail K-tile 15 (buf1), everything already staged
    asm volatile("s_waitcnt vmcnt(0)" ::: "memory");
    __builtin_amdgcn_s_barrier();
    __builtin_amdgcn_sched_barrier(0);
    {
        const int bb = 32768;
        RDA256(0, bb); RDB256(0, bb); MM256(0);
        RDB256(1, bb); MM256(1);
        RDA256(1, bb); RDB256(0, bb); MM256(2);
        RDB256(1, bb); MM256(3);
    }

    // ---- epilogue (no barrier needed: V-transpose uses shorts 0..18431, lagging
    //      tail reads are in buf1 at 32768.. -> disjoint) ----
    if (blockIdx.x < 8) {
        // q (x<4) / k (x 4..7), packed [bh][t][d]
        short* dst = reinterpret_cast<short*>(blockIdx.x < 4 ? (z ? o1a : o0a)
                                                             : (z ? o1b : o0b));
        const int b = (int)(M0 >> 10);
        const int t00 = ((int)M0 & 1023);
        const int hd00 = ((int)blockIdx.x & 3) * 256;
#pragma unroll
        for (int p = 0; p < 4; ++p) {
            const int Ah = p >> 1, Bh = p & 1;
            const int tr0 = t00 + Ah * 128 + rowblk + quad * 4;
#pragma unroll
            for (int nt = 0; nt < 2; ++nt) {
                const int hd = hd00 + Bh * 128 + colblk + nt * 16 + l16;
                const int h = hd >> 6, d = hd & 63;
                short* dp = dst + (long)(b * 16 + h) * 65536 + d;
#pragma unroll
                for (int mt = 0; mt < 4; ++mt)
#pragma unroll
                    for (int r = 0; r < 4; ++r)
                        dp[(long)(tr0 + mt * 16 + r) * 64] = f2bf(acc[p][mt][nt][r]);
            }
        }
    } else {
        // V: per-wave LDS transpose -> vT [bh][d][t], coalesced 16B stores
        short* vT = reinterpret_cast<short*>(z ? o1c : o0c);
        const int b = (int)(M0 >> 10);
        const int hd00 = ((int)blockIdx.x - 8) * 256;
        short* ws = smem + w * 2304;     // 32 cols x 72 shorts, wave-private
        const int c8 = (lane & 7) * 8;
        const int colr = lane >> 3;
#pragma unroll
        for (int p = 0; p < 4; ++p) {
            const int Ah = p >> 1, Bh = p & 1;
#pragma unroll
            for (int nt = 0; nt < 2; ++nt)
#pragma unroll
                for (int mt = 0; mt < 4; ++mt) {
                    uint2 uu;
                    uu.x = pk2(acc[p][mt][nt][0], acc[p][mt][nt][1]);
                    uu.y = pk2(acc[p][mt][nt][2], acc[p][mt][nt][3]);
                    *reinterpret_cast<uint2*>(&ws[(nt * 16 + l16) * 72 + mt * 16 + quad * 4]) = uu;
                }
            const int tb = ((int)M0 & 1023) + Ah * 128 + rowblk + c8;
#pragma unroll
            for (int q4 = 0; q4 < 4; ++q4) {
                const int col = q4 * 8 + colr;
                const int hd = hd00 + Bh * 128 + colblk + col;
                const int h = hd >> 6, d = hd & 63;
                short8 v = *reinterpret_cast<const short8*>(&ws[col * 72 + c8]);
                *reinterpret_cast<short8*>(&vT[(long)(b * 16 + h) * 65536 + (long)d * 1024 + tb]) = v;
            }
        }
    }
#undef SA256
#undef SB256
#undef RDA256
#undef RDB256
#undef MM256
}

// ---------------- out-proj GEMM: 128x128 gload_lds dbuf (unchanged structure) ----------------
template <int MODE>
__global__ __launch_bounds__(256)
void gemm_k(const bf16* __restrict__ A0g, const bf16* __restrict__ B0g,
            void* o0a, void* o0b, void* o0c,
            const bf16* __restrict__ A1g, const bf16* __restrict__ B1g,
            void* o1a, void* o1b, void* o1c, int N) {
    __shared__ short smem2[20480];
    const int z = blockIdx.z;
    const short* A = reinterpret_cast<const short*>(z ? A1g : A0g);
    const short* B = reinterpret_cast<const short*>(z ? B1g : B0g);
    const int tid  = threadIdx.x;
    const int lane = tid & 63;
    const int w    = tid >> 6;
    const int wr   = w >> 1;
    const int wc   = w & 1;
    const int quad = lane >> 4;
    const int l16  = lane & 15;
    const long bM = (long)blockIdx.y * 128;

    f32x4 acc[4][4] = {};

    const int sr  = lane >> 2;
    const int scs = ((lane & 3) ^ (sr & 3)) * 8;
    const short* Ag0 = A + (bM + 32 * w + sr) * 1024 + scs;
    const short* Ag1 = Ag0 + 16 * 1024;
    const short* Bg0 = B + ((long)blockIdx.x * 128 + 32 * w + sr) * 1024 + scs;
    const short* Bg1 = Bg0 + 16 * 1024;
    const int sq = (quad ^ (l16 & 3)) * 8;

    {
        short* sb = smem2;
        gload16(Ag0, sb + w * 1024);
        gload16(Ag1, sb + w * 1024 + 512);
        gload16(Bg0, sb + 4096 + w * 1024);
        gload16(Bg1, sb + 4096 + w * 1024 + 512);
    }
    __syncthreads();

    for (int iter = 0; iter < 32; ++iter) {
        const int cur = iter & 1;
        if (iter < 31) {
            const int koff = (iter + 1) * 32;
            short* sb = smem2 + (cur ^ 1) * 8192;
            gload16(Ag0 + koff, sb + w * 1024);
            gload16(Ag1 + koff, sb + w * 1024 + 512);
            gload16(Bg0 + koff, sb + 4096 + w * 1024);
            gload16(Bg1 + koff, sb + 4096 + w * 1024 + 512);
        }
        const short* Ab = smem2 + cur * 8192;
        const short* Bb = Ab + 4096;

        short8 af[4], bfr[4];
#pragma unroll
        for (int mt = 0; mt < 4; ++mt)
            af[mt] = *reinterpret_cast<const short8*>(&Ab[(wr * 64 + mt * 16 + l16) * 32 + sq]);
#pragma unroll
        for (int nt = 0; nt < 4; ++nt)
            bfr[nt] = *reinterpret_cast<const short8*>(&Bb[(wc * 64 + nt * 16 + l16) * 32 + sq]);
#pragma unroll
        for (int mt = 0; mt < 4; ++mt)
#pragma unroll
            for (int nt = 0; nt < 4; ++nt)
                acc[mt][nt] = MFMA_BF16(af[mt], bfr[nt], acc[mt][nt]);

        __syncthreads();
    }

    if (MODE == 1) {
        float* C = reinterpret_cast<float*>(z ? o1a : o0a);
        const long crow = bM + wr * 64 + quad * 4;
        const long ccol = (long)blockIdx.x * 128 + wc * 64 + l16;
#pragma unroll
        for (int mt = 0; mt < 4; ++mt)
#pragma unroll
            for (int nt = 0; nt < 4; ++nt)
#pragma unroll
                for (int r = 0; r < 4; ++r)
                    C[(crow + mt * 16 + r) * (long)N + ccol + nt * 16] = acc[mt][nt][r];
        return;
    }
    // (MODE 0 path retained for template completeness; not launched)
    if (blockIdx.x < 16) {
        short* dst = reinterpret_cast<short*>(blockIdx.x >= 8 ? (z ? o1b : o0b)
                                                              : (z ? o1a : o0a));
        const int hd0 = (int)(blockIdx.x & 7) * 128 + wc * 64;
        const int b = (int)(bM >> 10);
        const int t0 = ((int)bM & 1023) + wr * 64 + quad * 4;
#pragma unroll
        for (int nt = 0; nt < 4; ++nt) {
            const int hd = hd0 + nt * 16 + l16;
            const int h = hd >> 6, d = hd & 63;
            short* dp = dst + ((long)(b * 16 + h) * 1024) * 64 + d;
#pragma unroll
            for (int mt = 0; mt < 4; ++mt)
#pragma unroll
                for (int r = 0; r < 4; ++r)
                    dp[(long)(t0 + mt * 16 + r) * 64] = f2bf(acc[mt][nt][r]);
        }
    }
}

// ---------------- flash attention: counted-vmcnt pipeline + conflict-free swizzle ----------------
// Q,K packed [bh][t][d]; V^T [bh][d][t]. Swizzle f(row)=(row&3)|(bit3(row)<<2) uses row bits
// that vary across reading lanes -> K and V frag reads both conflict-free.
// Gates: vmcnt(4)+barrier before QK reads and before PV reads (stage-early); no vmcnt(0) drain.
__global__ __launch_bounds__(256)
void attn_kernel(const bf16* __restrict__ q0g, const bf16* __restrict__ k0g,
                 const bf16* __restrict__ v0g, bf16* __restrict__ o0g,
                 const bf16* __restrict__ q1g, const bf16* __restrict__ k1g,
                 const bf16* __restrict__ v1g, bf16* __restrict__ o1g) {
    __shared__ short smem[16384];
    const int bh = blockIdx.x;
    const int qt = blockIdx.y;
    const int z = blockIdx.z;
    const int b = bh >> 4, h = bh & 15;
    const int tid = threadIdx.x, lane = tid & 63, w = tid >> 6;
    const int quad = lane >> 4, l16 = lane & 15;

    const short* Qb = reinterpret_cast<const short*>(z ? q1g : q0g) + (long)bh * 1024 * 64;
    const short* Kb = reinterpret_cast<const short*>(z ? k1g : k0g) + (long)bh * 1024 * 64;
    const short* Vb = reinterpret_cast<const short*>(z ? v1g : v0g) + (long)bh * 64 * 1024;
    short* Ob = reinterpret_cast<short*>(z ? o1g : o0g);

    short8 qb[2][2];
#pragma unroll
    for (int qg = 0; qg < 2; ++qg) {
        const short* Qp = Qb + (long)(qt * 128 + qg * 64 + w * 16 + l16) * 64;
        qb[qg][0] = *reinterpret_cast<const short8*>(Qp + quad * 8);
        qb[qg][1] = *reinterpret_cast<const short8*>(Qp + 32 + quad * 8);
    }

    // staging: rows 16w+r8 (bit3=0, f=r8&3) and 16w+8+r8 (bit3=1, f=(r8&3)|4)
    const int r8  = lane >> 3;
    const int sc0 = ((lane & 7) ^ (r8 & 3)) * 8;
    const short* Kg0 = Kb + (long)(16 * w + r8) * 64 + sc0;
    const short* Kg1 = Kb + (long)(16 * w + 8 + r8) * 64 + (sc0 ^ 32);
    const short* Vg0 = Vb + (long)(16 * w + r8) * 1024 + sc0;
    const short* Vg1 = Vb + (long)(16 * w + 8 + r8) * 1024 + (sc0 ^ 32);

    const int jbase = 8 * (l16 >> 2) + (l16 & 3);
    // read-side swizzle constants (row bits expressed via l16)
    const int fKs = (l16 & 3) | (((l16 >> 2) & 1) << 2);
    const int s0  = (quad ^ fKs) * 8;
    const int fVs = (l16 & 3) | (((l16 >> 3) & 1) << 2);
    const int sv  = (quad ^ fVs) * 8;

    f32x4 o[2][4] = {};
    float li[2] = {0.f, 0.f};

    // prologue: tile 0 -> buf 0
    gload16(Kg0, smem + w * 1024); gload16(Kg1, smem + w * 1024 + 512);
    gload16(Vg0, smem + 4096 + w * 1024); gload16(Vg1, smem + 4096 + w * 1024 + 512);

#pragma unroll 1
    for (int iter = 0; iter < 16; ++iter) {
        const int cur = iter & 1;
        short* sb = smem + (cur ^ 1) * 8192;
        const bool pre = iter < 15;
        if (pre) {   // stage K(t+1) early
            const long ko = (long)(iter + 1) * 4096;
            gload16(Kg0 + ko, sb + w * 1024);
            gload16(Kg1 + ko, sb + w * 1024 + 512);
        }
        if (pre) { asm volatile("s_waitcnt vmcnt(4)" ::: "memory"); }
        else     { asm volatile("s_waitcnt vmcnt(2)" ::: "memory"); }
        __builtin_amdgcn_s_barrier();
        __builtin_amdgcn_sched_barrier(0);

        const short* Ks = smem + cur * 8192;
        const short* Vs = Ks + 4096;

        f32x4 st[2][4];
        __builtin_amdgcn_s_setprio(1);
#pragma unroll
        for (int g = 0; g < 4; ++g) {
            const int goff = (g >> 1) * 32 + (g & 1) * 4;
            const short* kr = Ks + (jbase + goff) * 64;
            short8 k0 = *reinterpret_cast<const short8*>(kr + s0);
            short8 k1 = *reinterpret_cast<const short8*>(kr + (s0 ^ 32));
#pragma unroll
            for (int qg = 0; qg < 2; ++qg) {
                f32x4 zf = {0.f, 0.f, 0.f, 0.f};
                zf = MFMA_BF16(k0, qb[qg][0], zf);
                zf = MFMA_BF16(k1, qb[qg][1], zf);
                st[qg][g] = zf;
            }
        }
        __builtin_amdgcn_s_setprio(0);

        if (pre) {   // stage V(t+1); flies under softmax
            const long vo = (long)(iter + 1) * 64;
            gload16(Vg0 + vo, sb + 4096 + w * 1024);
            gload16(Vg1 + vo, sb + 4096 + w * 1024 + 512);
        }

        union { unsigned int u[4]; short8 s; } f0[2], f1[2];
#pragma unroll
        for (int qg = 0; qg < 2; ++qg) {
            float p[4][4];
            float rs = 0.f;
#pragma unroll
            for (int g = 0; g < 4; ++g)
#pragma unroll
                for (int r = 0; r < 4; ++r) {
                    float e = exp2f(st[qg][g][r]);
                    p[g][r] = e;
                    rs += e;
                }
            li[qg] += rs;
            f0[qg].u[0] = pk2(p[0][0], p[0][1]); f0[qg].u[1] = pk2(p[0][2], p[0][3]);
            f0[qg].u[2] = pk2(p[1][0], p[1][1]); f0[qg].u[3] = pk2(p[1][2], p[1][3]);
            f1[qg].u[0] = pk2(p[2][0], p[2][1]); f1[qg].u[1] = pk2(p[2][2], p[2][3]);
            f1[qg].u[2] = pk2(p[3][0], p[3][1]); f1[qg].u[3] = pk2(p[3][2], p[3][3]);
        }

        if (pre) { asm volatile("s_waitcnt vmcnt(4)" ::: "memory"); }
        else     { asm volatile("s_waitcnt vmcnt(0)" ::: "memory"); }
        __builtin_amdgcn_s_barrier();
        __builtin_amdgcn_sched_barrier(0);

        __builtin_amdgcn_s_setprio(1);
#pragma unroll
        for (int dt = 0; dt < 4; ++dt) {
            const short* vr = Vs + (dt * 16 + l16) * 64;
            short8 v0 = *reinterpret_cast<const short8*>(vr + sv);
            short8 v1 = *reinterpret_cast<const short8*>(vr + (sv ^ 32));
#pragma unroll
            for (int qg = 0; qg < 2; ++qg) {
                o[qg][dt] = MFMA_BF16(v0, f0[qg].s, o[qg][dt]);
                o[qg][dt] = MFMA_BF16(v1, f1[qg].s, o[qg][dt]);
            }
        }
        __builtin_amdgcn_s_setprio(0);
    }

    __syncthreads();   // O-staging below reuses smem regions that overlap K/V bufs

#pragma unroll
    for (int qg = 0; qg < 2; ++qg) {
        li[qg] += __shfl_xor(li[qg], 16);
        li[qg] += __shfl_xor(li[qg], 32);
    }

#pragma unroll
    for (int qg = 0; qg < 2; ++qg) {
        short* Os = smem + qg * 5120 + w * 1280;
        const float rl = 1.0f / li[qg];
#pragma unroll
        for (int dt = 0; dt < 4; ++dt) {
            uint2 uu;
            uu.x = pk2(o[qg][dt][0] * rl, o[qg][dt][1] * rl);
            uu.y = pk2(o[qg][dt][2] * rl, o[qg][dt][3] * rl);
            *reinterpret_cast<uint2*>(&Os[l16 * 80 + dt * 16 + quad * 4]) = uu;
        }
#pragma unroll
        for (int p = 0; p < 2; ++p) {
            int row = p * 8 + (lane >> 3);
            int ch = (lane & 7) * 8;
            short8 v = *reinterpret_cast<const short8*>(&Os[row * 80 + ch]);
            *reinterpret_cast<short8*>(&Ob[((long)(b * 1024) + qt * 128 + qg * 64 + w * 16 + row) * 1024 + h * 64 + ch]) = v;
        }
    }
}

extern "C" void kernel_launch(void* const* d_in, const int* in_sizes, int n_in,
                              void* d_out, int out_size, void* d_ws, size_t ws_size,
                              hipStream_t stream) {
    const float* x     = (const float*)d_in[0];
    const float* y     = (const float*)d_in[1];
    const float* Wqkv1 = (const float*)d_in[2];
    const float* Wqkv2 = (const float*)d_in[3];
    const float* Wout1 = (const float*)d_in[4];
    const float* Wout2 = (const float*)d_in[5];

    char* ws = (char*)d_ws;
    bf16* Wqkv1b = (bf16*)(ws + 0);          // 6291456
    bf16* Wqkv2b = (bf16*)(ws + 6291456);    // 6291456
    bf16* Wout1b = (bf16*)(ws + 12582912);   // 2097152
    bf16* Wout2b = (bf16*)(ws + 14680064);   // 2097152
    bf16* xb     = (bf16*)(ws + 16777216);   // 8388608
    bf16* yb     = (bf16*)(ws + 25165824);   // 8388608
    bf16* q1     = (bf16*)(ws + 33554432);   // 8388608  packed [bh][t][d]
    bf16* k1     = (bf16*)(ws + 41943040);   // 8388608
    bf16* v1T    = (bf16*)(ws + 50331648);   // 8388608  [bh][d][t]
    bf16* q2     = (bf16*)(ws + 58720256);   // 8388608
    bf16* k2     = (bf16*)(ws + 67108864);   // 8388608
    bf16* v2T    = (bf16*)(ws + 75497472);   // 8388608 -> 83886080 (80 MB)
    bf16* xo     = xb;                       // xb dead after qkv GEMM
    bf16* yo     = yb;

    static bool s_attr = false;
    if (!s_attr) {
        (void)hipFuncSetAttribute(reinterpret_cast<const void*>(&gemm_qkv256),
                                  hipFuncAttributeMaxDynamicSharedMemorySize, 131072);
        s_attr = true;
    }

    // 1. all converts (x, y, Wout, Wqkv-permuted+scaled)
    cvt_fused<<<dim3(4096, 6), 256, 0, stream>>>(x, y, Wout1, Wout2, Wqkv1, Wqkv2,
                                                 xb, yb, Wout1b, Wout2b, Wqkv1b, Wqkv2b);

    // 2. qkv GEMM: 256x256 8-phase counted-vmcnt pipeline -> q,k packed + vT; both streams
    gemm_qkv256<<<dim3(12, 16, 2), 512, 131072, stream>>>(xb, Wqkv1b, q1, k1, v1T,
                                                          yb, Wqkv2b, q2, k2, v2T);

    // 3. cross attention: z=0: softmax(q2 k1^T) v1 -> xo ; z=1: softmax(q1 k2^T) v2 -> yo
    attn_kernel<<<dim3(64, 8, 2), 256, 0, stream>>>(q2, k1, v1T, xo,
                                                    q1, k2, v2T, yo);

    // 4. output projections (gload_lds pipeline, fp32 epilogue)
    gemm_k<1><<<dim3(8, 32, 2), 256, 0, stream>>>(xo, Wout1b, (float*)d_out, nullptr, nullptr,
                                                  yo, Wout2b, ((float*)d_out) + 4194304, nullptr, nullptr,
                                                  1024);
}

// Round 4
// 241.914 us; speedup vs baseline: 1.1171x; 1.0910x over previous
//
#include <hip/hip_runtime.h>
#include <hip/hip_bf16.h>

typedef __hip_bfloat16 bf16;
typedef __attribute__((ext_vector_type(8))) short short8;
typedef __attribute__((ext_vector_type(4))) short short4v;
typedef __attribute__((ext_vector_type(4))) float f32x4;

#define MFMA_BF16(a, b, c) __builtin_amdgcn_mfma_f32_16x16x32_bf16((a), (b), (c), 0, 0, 0)

// 1/sqrt(E/H) * log2(e) folded into Wqkv q-rows: softmax exps become plain exp2
#define QSCALE 0.1803368860111270f

__device__ __forceinline__ short f2bf(float f) {
    union { bf16 h; short s; } u;
    u.h = __float2bfloat16(f);
    return u.s;
}

#if defined(__has_builtin) && __has_builtin(__builtin_amdgcn_cvt_pk_bf16_f32)
typedef __attribute__((ext_vector_type(2))) __bf16 bf16x2_t;
__device__ __forceinline__ unsigned int pk2(float a, float b) {
    union { bf16x2_t v; unsigned int u; } x;
    x.v = __builtin_amdgcn_cvt_pk_bf16_f32(a, b);
    return x.u;
}
#else
__device__ __forceinline__ unsigned int pk2(float a, float b) {
    union { bf16 h[2]; unsigned int u; } x;
    x.h[0] = __float2bfloat16(a);
    x.h[1] = __float2bfloat16(b);
    return x.u;
}
#endif

// raw v_exp_f32 (skip LLVM's denormal-range fixup: scores are far from -126)
#if defined(__has_builtin) && __has_builtin(__builtin_amdgcn_exp2f)
#define EXP2F(x) __builtin_amdgcn_exp2f(x)
#else
#define EXP2F(x) exp2f(x)
#endif

// async global->LDS, 16B per lane; dest = wave-uniform base + lane*16 (linear)
__device__ __forceinline__ void gload16(const void* g, void* l) {
    __builtin_amdgcn_global_load_lds(
        (const __attribute__((address_space(1))) unsigned int*)g,
        (__attribute__((address_space(3))) unsigned int*)l, 16, 0, 0);
}

// ---------------- ALL converts in one dispatch (grid.y selects tensor / mode) ----------------
// (reverted to the proven f2bf path)
__global__ void cvt_fused(const float* __restrict__ x, const float* __restrict__ y,
                          const float* __restrict__ wo1, const float* __restrict__ wo2,
                          const float* __restrict__ wq1, const float* __restrict__ wq2,
                          bf16* __restrict__ ox, bf16* __restrict__ oy,
                          bf16* __restrict__ oo1, bf16* __restrict__ oo2,
                          bf16* __restrict__ oq1, bf16* __restrict__ oq2) {
    const int yb = blockIdx.y;
    if (yb < 4) {
        int i = blockIdx.x * 256 + threadIdx.x;
        const float* src; bf16* dst; int n4;
        switch (yb) {
            case 0:  src = x;   dst = ox;  n4 = 1048576; break;
            case 1:  src = y;   dst = oy;  n4 = 1048576; break;
            case 2:  src = wo1; dst = oo1; n4 = 262144;  break;
            default: src = wo2; dst = oo2; n4 = 262144;  break;
        }
        if (i >= n4) return;
        float4 f = reinterpret_cast<const float4*>(src)[i];
        short4v s;
        s.x = f2bf(f.x); s.y = f2bf(f.y); s.z = f2bf(f.z); s.w = f2bf(f.w);
        reinterpret_cast<short4v*>(dst)[i] = s;
    } else {
        // dest row n' = comp*1024 + h*64 + d  <-  src row d*48 + comp*16 + h
        const int np = blockIdx.x;
        if (np >= 3072) return;
        const int comp = np >> 10, rem = np & 1023, h = rem >> 6, d = rem & 63;
        const int srow = d * 48 + comp * 16 + h;
        const float* src = ((yb == 5) ? wq2 : wq1) + (long)srow * 1024;
        bf16* dst = ((yb == 5) ? oq2 : oq1) + (long)np * 1024;
        const float sc = (comp == 0) ? QSCALE : 1.0f;
        int t = threadIdx.x;
        float4 f = reinterpret_cast<const float4*>(src)[t];
        short4v s;
        s.x = f2bf(f.x * sc); s.y = f2bf(f.y * sc); s.z = f2bf(f.z * sc); s.w = f2bf(f.w * sc);
        reinterpret_cast<short4v*>(dst)[t] = s;
    }
}

// ---------------- 256x256 8-phase qkv GEMM (T2+T3+T4+T5), BK=64, 8 waves ----------------
// (unchanged — passed twice at absmax 4.9e-4)
#define GATE4 do { asm volatile("s_waitcnt vmcnt(4)" ::: "memory"); \
    __builtin_amdgcn_s_barrier(); __builtin_amdgcn_sched_barrier(0); } while (0)

__global__ __launch_bounds__(512, 2)
void gemm_qkv256(const bf16* __restrict__ A0g, const bf16* __restrict__ B0g,
                 void* o0a, void* o0b, void* o0c,
                 const bf16* __restrict__ A1g, const bf16* __restrict__ B1g,
                 void* o1a, void* o1b, void* o1c) {
    extern __shared__ short smem[];   // 65536 shorts = 128KB
    const int z = blockIdx.z;
    const short* A = reinterpret_cast<const short*>(z ? A1g : A0g);
    const short* B = reinterpret_cast<const short*>(z ? B1g : B0g);
    const int tid  = threadIdx.x;
    const int lane = tid & 63;
    const int w    = tid >> 6;        // 0..7
    const int quad = lane >> 4;
    const int l16  = lane & 15;
    const long M0 = (long)blockIdx.y * 256;
    const long N0 = (long)blockIdx.x * 256;

    const int rowblk = (w >> 2) * 64;     // wave M-offset within 128-row region
    const int colblk = (w & 3) * 32;      // wave N-offset within 128-col region
    const int cA0  = (quad ^ (l16 & 7)) * 8;            // kk=0 chunk (shorts); kk=1 -> ^32
    const int aoff = (rowblk + l16) * 64;
    const int boff = 16384 + (colblk + l16) * 64;       // B halves live at +16384/+24576
    const int w512 = w * 512;

    const short* Asrc = A + (M0 + w * 8 + (lane >> 3)) * 1024 + ((lane & 7) ^ (lane >> 3)) * 8;
    const short* Bsrc = B + (N0 + w * 8 + (lane >> 3)) * 1024 + ((lane & 7) ^ (lane >> 3)) * 8;

    f32x4 acc[4][4][2] = {};
    short8 af[4][2], bfv[2][2];

#define SA256(half, tt, nbase) do { \
    const short* _s = Asrc + (half) * 131072 + (tt) * 64; \
    short* _d = smem + (nbase) + (half) * 8192 + w512; \
    gload16(_s, _d); gload16(_s + 65536, _d + 4096); } while (0)
#define SB256(half, tt, nbase) do { \
    const short* _s = Bsrc + (half) * 131072 + (tt) * 64; \
    short* _d = smem + (nbase) + 16384 + (half) * 8192 + w512; \
    gload16(_s, _d); gload16(_s + 65536, _d + 4096); } while (0)
#define RDA256(Ah, bbv) do { \
    _Pragma("unroll") for (int mt = 0; mt < 4; ++mt) { \
        const short* _p = &smem[(bbv) + (Ah) * 8192 + aoff + mt * 1024]; \
        af[mt][0] = *reinterpret_cast<const short8*>(_p + cA0); \
        af[mt][1] = *reinterpret_cast<const short8*>(_p + (cA0 ^ 32)); } } while (0)
#define RDB256(Bh, bbv) do { \
    _Pragma("unroll") for (int nt = 0; nt < 2; ++nt) { \
        const short* _p = &smem[(bbv) + (Bh) * 8192 + boff + nt * 1024]; \
        bfv[nt][0] = *reinterpret_cast<const short8*>(_p + cA0); \
        bfv[nt][1] = *reinterpret_cast<const short8*>(_p + (cA0 ^ 32)); } } while (0)
#define MM256(p) do { \
    __builtin_amdgcn_s_setprio(1); \
    _Pragma("unroll") for (int mt = 0; mt < 4; ++mt) \
    _Pragma("unroll") for (int nt = 0; nt < 2; ++nt) { \
        acc[p][mt][nt] = MFMA_BF16(af[mt][0], bfv[nt][0], acc[p][mt][nt]); \
        acc[p][mt][nt] = MFMA_BF16(af[mt][1], bfv[nt][1], acc[p][mt][nt]); } \
    __builtin_amdgcn_s_setprio(0); } while (0)

    // prologue: K-tile 0 fully staged into buf0 (stream order A0,B0,B1,A1)
    SA256(0, 0, 0); SB256(0, 0, 0); SB256(1, 0, 0); SA256(1, 0, 0);

#pragma unroll 1
    for (int t = 0; t < 15; ++t) {
        const int bb = (t & 1) << 15;
        const int nb = bb ^ 32768;
        GATE4;
        SA256(0, t + 1, nb);
        RDA256(0, bb); RDB256(0, bb);
        __builtin_amdgcn_sched_barrier(0);
        MM256(0);
        GATE4;
        SB256(0, t + 1, nb);
        RDB256(1, bb);
        __builtin_amdgcn_sched_barrier(0);
        MM256(1);
        GATE4;
        SB256(1, t + 1, nb);
        RDA256(1, bb); RDB256(0, bb);
        __builtin_amdgcn_sched_barrier(0);
        MM256(2);
        SA256(1, t + 1, nb);
        RDB256(1, bb);
        __builtin_amdgcn_sched_barrier(0);
        MM256(3);
    }
    asm volatile("s_waitcnt vmcnt(0)" ::: "memory");
    __builtin_amdgcn_s_barrier();
    __builtin_amdgcn_sched_barrier(0);
    {
        const int bb = 32768;
        RDA256(0, bb); RDB256(0, bb); MM256(0);
        RDB256(1, bb); MM256(1);
        RDA256(1, bb); RDB256(0, bb); MM256(2);
        RDB256(1, bb); MM256(3);
    }

    if (blockIdx.x < 8) {
        // q (x<4) / k (x 4..7), packed [bh][t][d]
        short* dst = reinterpret_cast<short*>(blockIdx.x < 4 ? (z ? o1a : o0a)
                                                             : (z ? o1b : o0b));
        const int b = (int)(M0 >> 10);
        const int t00 = ((int)M0 & 1023);
        const int hd00 = ((int)blockIdx.x & 3) * 256;
#pragma unroll
        for (int p = 0; p < 4; ++p) {
            const int Ah = p >> 1, Bh = p & 1;
            const int tr0 = t00 + Ah * 128 + rowblk + quad * 4;
#pragma unroll
            for (int nt = 0; nt < 2; ++nt) {
                const int hd = hd00 + Bh * 128 + colblk + nt * 16 + l16;
                const int h = hd >> 6, d = hd & 63;
                short* dp = dst + (long)(b * 16 + h) * 65536 + d;
#pragma unroll
                for (int mt = 0; mt < 4; ++mt)
#pragma unroll
                    for (int r = 0; r < 4; ++r)
                        dp[(long)(tr0 + mt * 16 + r) * 64] = f2bf(acc[p][mt][nt][r]);
            }
        }
    } else {
        // V: per-wave LDS transpose -> vT [bh][d][t], coalesced 16B stores
        short* vT = reinterpret_cast<short*>(z ? o1c : o0c);
        const int b = (int)(M0 >> 10);
        const int hd00 = ((int)blockIdx.x - 8) * 256;
        short* ws = smem + w * 2304;     // 32 cols x 72 shorts, wave-private
        const int c8 = (lane & 7) * 8;
        const int colr = lane >> 3;
#pragma unroll
        for (int p = 0; p < 4; ++p) {
            const int Ah = p >> 1, Bh = p & 1;
#pragma unroll
            for (int nt = 0; nt < 2; ++nt)
#pragma unroll
                for (int mt = 0; mt < 4; ++mt) {
                    uint2 uu;
                    uu.x = pk2(acc[p][mt][nt][0], acc[p][mt][nt][1]);
                    uu.y = pk2(acc[p][mt][nt][2], acc[p][mt][nt][3]);
                    *reinterpret_cast<uint2*>(&ws[(nt * 16 + l16) * 72 + mt * 16 + quad * 4]) = uu;
                }
            const int tb = ((int)M0 & 1023) + Ah * 128 + rowblk + c8;
#pragma unroll
            for (int q4 = 0; q4 < 4; ++q4) {
                const int col = q4 * 8 + colr;
                const int hd = hd00 + Bh * 128 + colblk + col;
                const int h = hd >> 6, d = hd & 63;
                short8 v = *reinterpret_cast<const short8*>(&ws[col * 72 + c8]);
                *reinterpret_cast<short8*>(&vT[(long)(b * 16 + h) * 65536 + (long)d * 1024 + tb]) = v;
            }
        }
    }
#undef SA256
#undef SB256
#undef RDA256
#undef RDB256
#undef MM256
}

// ---------------- out-proj GEMM: 128x128, TRIPLE-buffer counted-vmcnt pipeline ----------------
// 3 bufs: staging tile t+1 targets beta(t+1)=beta(t-2), whose readers (compute t-2) all
// finished before barrier(t-1), which the staging wave has provably passed -> race-free.
// One s_barrier/iter; vmcnt(4) waits tile t (issued a full iter earlier -> latency hidden).
__global__ __launch_bounds__(256)
void gemm_out(const bf16* __restrict__ A0g, const bf16* __restrict__ B0g, float* __restrict__ C0,
              const bf16* __restrict__ A1g, const bf16* __restrict__ B1g, float* __restrict__ C1) {
    __shared__ short smem2[24576];   // 3 bufs x (A 4096 + B 4096)
    const int z = blockIdx.z;
    const short* A = reinterpret_cast<const short*>(z ? A1g : A0g);
    const short* B = reinterpret_cast<const short*>(z ? B1g : B0g);
    const int tid  = threadIdx.x;
    const int lane = tid & 63;
    const int w    = tid >> 6;
    const int wr   = w >> 1;
    const int wc   = w & 1;
    const int quad = lane >> 4;
    const int l16  = lane & 15;
    const long bM = (long)blockIdx.y * 128;

    f32x4 acc[4][4] = {};

    const int sr  = lane >> 2;
    const int scs = ((lane & 3) ^ (sr & 3)) * 8;
    const short* Ag0 = A + (bM + 32 * w + sr) * 1024 + scs;
    const short* Ag1 = Ag0 + 16 * 1024;
    const short* Bg0 = B + ((long)blockIdx.x * 128 + 32 * w + sr) * 1024 + scs;
    const short* Bg1 = Bg0 + 16 * 1024;
    const int sq = (quad ^ (l16 & 3)) * 8;

    {   // prologue: tile 0 -> buf 0
        short* sb = smem2;
        gload16(Ag0, sb + w * 1024);
        gload16(Ag1, sb + w * 1024 + 512);
        gload16(Bg0, sb + 4096 + w * 1024);
        gload16(Bg1, sb + 4096 + w * 1024 + 512);
    }

    int bcur = 0;
#pragma unroll 1
    for (int iter = 0; iter < 32; ++iter) {
        int bnext = bcur + 1; if (bnext == 3) bnext = 0;
        if (iter < 31) {
            const int koff = (iter + 1) * 32;
            short* sb = smem2 + bnext * 8192;
            gload16(Ag0 + koff, sb + w * 1024);
            gload16(Ag1 + koff, sb + w * 1024 + 512);
            gload16(Bg0 + koff, sb + 4096 + w * 1024);
            gload16(Bg1 + koff, sb + 4096 + w * 1024 + 512);
            asm volatile("s_waitcnt vmcnt(4)" ::: "memory");
        } else {
            asm volatile("s_waitcnt vmcnt(0)" ::: "memory");
        }
        __builtin_amdgcn_s_barrier();
        __builtin_amdgcn_sched_barrier(0);

        const short* Ab = smem2 + bcur * 8192;
        const short* Bb = Ab + 4096;

        short8 af[4], bfr[4];
#pragma unroll
        for (int mt = 0; mt < 4; ++mt)
            af[mt] = *reinterpret_cast<const short8*>(&Ab[(wr * 64 + mt * 16 + l16) * 32 + sq]);
#pragma unroll
        for (int nt = 0; nt < 4; ++nt)
            bfr[nt] = *reinterpret_cast<const short8*>(&Bb[(wc * 64 + nt * 16 + l16) * 32 + sq]);
        __builtin_amdgcn_s_setprio(1);
#pragma unroll
        for (int mt = 0; mt < 4; ++mt)
#pragma unroll
            for (int nt = 0; nt < 4; ++nt)
                acc[mt][nt] = MFMA_BF16(af[mt], bfr[nt], acc[mt][nt]);
        __builtin_amdgcn_s_setprio(0);
        bcur = bnext;
    }

    float* C = z ? C1 : C0;
    const long crow = bM + wr * 64 + quad * 4;
    const long ccol = (long)blockIdx.x * 128 + wc * 64 + l16;
#pragma unroll
    for (int mt = 0; mt < 4; ++mt)
#pragma unroll
        for (int nt = 0; nt < 4; ++nt)
#pragma unroll
            for (int r = 0; r < 4; ++r)
                C[(crow + mt * 16 + r) * 1024L + ccol + nt * 16] = acc[mt][nt][r];
}

// ---------------- flash attention: TRIPLE-buffer single-barrier pipeline + raw v_exp_f32 ----------------
// Q,K packed [bh][t][d]; V^T [bh][d][t]. Conflict-free swizzle f(row)=(row&3)|(bit3(row)<<2).
// Per iter: stage tile t+1 -> beta(t+1) (4 loads), vmcnt(4) (waits tile t, issued a full
// iter ago), one s_barrier, then QK+softmax+PV read beta(t). Race-free: beta(t+1)'s prior
// readers ran in iter t-2, complete before barrier(t-1) which the staging wave passed.
__global__ __launch_bounds__(256)
void attn_kernel(const bf16* __restrict__ q0g, const bf16* __restrict__ k0g,
                 const bf16* __restrict__ v0g, bf16* __restrict__ o0g,
                 const bf16* __restrict__ q1g, const bf16* __restrict__ k1g,
                 const bf16* __restrict__ v1g, bf16* __restrict__ o1g) {
    __shared__ short smem[24576];   // 3 bufs x (K 4096 + V 4096) shorts = 48KB
    const int bh = blockIdx.x;
    const int qt = blockIdx.y;
    const int z = blockIdx.z;
    const int b = bh >> 4, h = bh & 15;
    const int tid = threadIdx.x, lane = tid & 63, w = tid >> 6;
    const int quad = lane >> 4, l16 = lane & 15;

    const short* Qb = reinterpret_cast<const short*>(z ? q1g : q0g) + (long)bh * 1024 * 64;
    const short* Kb = reinterpret_cast<const short*>(z ? k1g : k0g) + (long)bh * 1024 * 64;
    const short* Vb = reinterpret_cast<const short*>(z ? v1g : v0g) + (long)bh * 64 * 1024;
    short* Ob = reinterpret_cast<short*>(z ? o1g : o0g);

    short8 qb[2][2];
#pragma unroll
    for (int qg = 0; qg < 2; ++qg) {
        const short* Qp = Qb + (long)(qt * 128 + qg * 64 + w * 16 + l16) * 64;
        qb[qg][0] = *reinterpret_cast<const short8*>(Qp + quad * 8);
        qb[qg][1] = *reinterpret_cast<const short8*>(Qp + 32 + quad * 8);
    }

    // staging: rows 16w+r8 (bit3=0, f=r8&3) and 16w+8+r8 (bit3=1, f=(r8&3)|4)
    const int r8  = lane >> 3;
    const int sc0 = ((lane & 7) ^ (r8 & 3)) * 8;
    const short* Kg0 = Kb + (long)(16 * w + r8) * 64 + sc0;
    const short* Kg1 = Kb + (long)(16 * w + 8 + r8) * 64 + (sc0 ^ 32);
    const short* Vg0 = Vb + (long)(16 * w + r8) * 1024 + sc0;
    const short* Vg1 = Vb + (long)(16 * w + 8 + r8) * 1024 + (sc0 ^ 32);

    const int jbase = 8 * (l16 >> 2) + (l16 & 3);
    // read-side swizzle constants (row bits expressed via l16)
    const int fKs = (l16 & 3) | (((l16 >> 2) & 1) << 2);
    const int s0  = (quad ^ fKs) * 8;
    const int fVs = (l16 & 3) | (((l16 >> 3) & 1) << 2);
    const int sv  = (quad ^ fVs) * 8;

    f32x4 o[2][4] = {};
    float li[2] = {0.f, 0.f};

    // prologue: tile 0 -> buf 0
    gload16(Kg0, smem + w * 1024); gload16(Kg1, smem + w * 1024 + 512);
    gload16(Vg0, smem + 4096 + w * 1024); gload16(Vg1, smem + 4096 + w * 1024 + 512);

    int bcur = 0;
#pragma unroll 1
    for (int iter = 0; iter < 16; ++iter) {
        int bnext = bcur + 1; if (bnext == 3) bnext = 0;
        if (iter < 15) {   // stage tile t+1 into beta(t+1)
            short* sb = smem + bnext * 8192;
            const long ko = (long)(iter + 1) * 4096;   // K: 64 t-rows * 64 shorts
            const long vo = (long)(iter + 1) * 64;     // V: within-row t offset
            gload16(Kg0 + ko, sb + w * 1024);
            gload16(Kg1 + ko, sb + w * 1024 + 512);
            gload16(Vg0 + vo, sb + 4096 + w * 1024);
            gload16(Vg1 + vo, sb + 4096 + w * 1024 + 512);
            asm volatile("s_waitcnt vmcnt(4)" ::: "memory");
        } else {
            asm volatile("s_waitcnt vmcnt(0)" ::: "memory");
        }
        __builtin_amdgcn_s_barrier();
        __builtin_amdgcn_sched_barrier(0);

        const short* Ks = smem + bcur * 8192;
        const short* Vs = Ks + 4096;

        f32x4 st[2][4];
        __builtin_amdgcn_s_setprio(1);
#pragma unroll
        for (int g = 0; g < 4; ++g) {
            const int goff = (g >> 1) * 32 + (g & 1) * 4;
            const short* kr = Ks + (jbase + goff) * 64;
            short8 k0 = *reinterpret_cast<const short8*>(kr + s0);
            short8 k1 = *reinterpret_cast<const short8*>(kr + (s0 ^ 32));
#pragma unroll
            for (int qg = 0; qg < 2; ++qg) {
                f32x4 zf = {0.f, 0.f, 0.f, 0.f};
                zf = MFMA_BF16(k0, qb[qg][0], zf);
                zf = MFMA_BF16(k1, qb[qg][1], zf);
                st[qg][g] = zf;
            }
        }
        __builtin_amdgcn_s_setprio(0);

        union { unsigned int u[4]; short8 s; } f0[2], f1[2];
#pragma unroll
        for (int qg = 0; qg < 2; ++qg) {
            float p[4][4];
            float rs = 0.f;
#pragma unroll
            for (int g = 0; g < 4; ++g)
#pragma unroll
                for (int r = 0; r < 4; ++r) {
                    float e = EXP2F(st[qg][g][r]);
                    p[g][r] = e;
                    rs += e;
                }
            li[qg] += rs;
            f0[qg].u[0] = pk2(p[0][0], p[0][1]); f0[qg].u[1] = pk2(p[0][2], p[0][3]);
            f0[qg].u[2] = pk2(p[1][0], p[1][1]); f0[qg].u[3] = pk2(p[1][2], p[1][3]);
            f1[qg].u[0] = pk2(p[2][0], p[2][1]); f1[qg].u[1] = pk2(p[2][2], p[2][3]);
            f1[qg].u[2] = pk2(p[3][0], p[3][1]); f1[qg].u[3] = pk2(p[3][2], p[3][3]);
        }

        __builtin_amdgcn_s_setprio(1);
#pragma unroll
        for (int dt = 0; dt < 4; ++dt) {
            const short* vr = Vs + (dt * 16 + l16) * 64;
            short8 v0 = *reinterpret_cast<const short8*>(vr + sv);
            short8 v1 = *reinterpret_cast<const short8*>(vr + (sv ^ 32));
#pragma unroll
            for (int qg = 0; qg < 2; ++qg) {
                o[qg][dt] = MFMA_BF16(v0, f0[qg].s, o[qg][dt]);
                o[qg][dt] = MFMA_BF16(v1, f1[qg].s, o[qg][dt]);
            }
        }
        __builtin_amdgcn_s_setprio(0);
        bcur = bnext;
    }

    __syncthreads();   // O-staging below reuses smem regions that overlap K/V bufs

#pragma unroll
    for (int qg = 0; qg < 2; ++qg) {
        li[qg] += __shfl_xor(li[qg], 16);
        li[qg] += __shfl_xor(li[qg], 32);
    }

#pragma unroll
    for (int qg = 0; qg < 2; ++qg) {
        short* Os = smem + qg * 5120 + w * 1280;
        const float rl = 1.0f / li[qg];
#pragma unroll
        for (int dt = 0; dt < 4; ++dt) {
            uint2 uu;
            uu.x = pk2(o[qg][dt][0] * rl, o[qg][dt][1] * rl);
            uu.y = pk2(o[qg][dt][2] * rl, o[qg][dt][3] * rl);
            *reinterpret_cast<uint2*>(&Os[l16 * 80 + dt * 16 + quad * 4]) = uu;
        }
#pragma unroll
        for (int p = 0; p < 2; ++p) {
            int row = p * 8 + (lane >> 3);
            int ch = (lane & 7) * 8;
            short8 v = *reinterpret_cast<const short8*>(&Os[row * 80 + ch]);
            *reinterpret_cast<short8*>(&Ob[((long)(b * 1024) + qt * 128 + qg * 64 + w * 16 + row) * 1024 + h * 64 + ch]) = v;
        }
    }
}

extern "C" void kernel_launch(void* const* d_in, const int* in_sizes, int n_in,
                              void* d_out, int out_size, void* d_ws, size_t ws_size,
                              hipStream_t stream) {
    const float* x     = (const float*)d_in[0];
    const float* y     = (const float*)d_in[1];
    const float* Wqkv1 = (const float*)d_in[2];
    const float* Wqkv2 = (const float*)d_in[3];
    const float* Wout1 = (const float*)d_in[4];
    const float* Wout2 = (const float*)d_in[5];

    char* ws = (char*)d_ws;
    bf16* Wqkv1b = (bf16*)(ws + 0);          // 6291456
    bf16* Wqkv2b = (bf16*)(ws + 6291456);    // 6291456
    bf16* Wout1b = (bf16*)(ws + 12582912);   // 2097152
    bf16* Wout2b = (bf16*)(ws + 14680064);   // 2097152
    bf16* xb     = (bf16*)(ws + 16777216);   // 8388608
    bf16* yb     = (bf16*)(ws + 25165824);   // 8388608
    bf16* q1     = (bf16*)(ws + 33554432);   // 8388608  packed [bh][t][d]
    bf16* k1     = (bf16*)(ws + 41943040);   // 8388608
    bf16* v1T    = (bf16*)(ws + 50331648);   // 8388608  [bh][d][t]
    bf16* q2     = (bf16*)(ws + 58720256);   // 8388608
    bf16* k2     = (bf16*)(ws + 67108864);   // 8388608
    bf16* v2T    = (bf16*)(ws + 75497472);   // 8388608 -> 83886080 (80 MB)
    bf16* xo     = xb;                       // xb dead after qkv GEMM
    bf16* yo     = yb;

    static bool s_attr = false;
    if (!s_attr) {
        (void)hipFuncSetAttribute(reinterpret_cast<const void*>(&gemm_qkv256),
                                  hipFuncAttributeMaxDynamicSharedMemorySize, 131072);
        s_attr = true;
    }

    // 1. all converts (x, y, Wout, Wqkv-permuted+scaled)
    cvt_fused<<<dim3(4096, 6), 256, 0, stream>>>(x, y, Wout1, Wout2, Wqkv1, Wqkv2,
                                                 xb, yb, Wout1b, Wout2b, Wqkv1b, Wqkv2b);

    // 2. qkv GEMM: 256x256 8-phase counted-vmcnt pipeline -> q,k packed + vT; both streams
    gemm_qkv256<<<dim3(12, 16, 2), 512, 131072, stream>>>(xb, Wqkv1b, q1, k1, v1T,
                                                          yb, Wqkv2b, q2, k2, v2T);

    // 3. cross attention: z=0: softmax(q2 k1^T) v1 -> xo ; z=1: softmax(q1 k2^T) v2 -> yo
    attn_kernel<<<dim3(64, 8, 2), 256, 0, stream>>>(q2, k1, v1T, xo,
                                                    q1, k2, v2T, yo);

    // 4. output projections (triple-buffer counted-vmcnt pipeline, fp32 epilogue)
    gemm_out<<<dim3(8, 32, 2), 256, 0, stream>>>(xo, Wout1b, (float*)d_out,
                                                 yo, Wout2b, ((float*)d_out) + 4194304);
}